// Round 4
// baseline (214.913 us; speedup 1.0000x reference)
//
#include <hip/hip_runtime.h>

// ALSTM: adaptive-computation-time LSTM (halts at t=1 for this data; exact
// for general n).
// R15: grid-shrink + flat sync. Evidence: R14 warm dispatches fetch ~0 B
// from HBM and still take 55 us == cold time == R12/R0 time. The floor is
// per-WG fixed cost (launch ramp serialized into everyone's critical path
// by the grid sync), not data movement.
//  - NBLK 256 -> 128 (512 thr): halves the WG ramp the barrier must wait
//    out. Each wave owns 8 gate rows, W_hh bf16-packed in 128 VGPRs
//    (t=0 dot fused fp32 during packing; only t>=1 uses bf16).
//  - All-to-all barrier, block0 hub + mailbox DELETED: every block polls
//    all 128 arrive slots, then computes the halt dot REDUNDANTLY from
//    the h-exchange it must read anyway (w_halt held in registers).
//    One fabric round trip per step instead of two.
//  - hbar in per-thread registers (identical in all blocks; only b==0
//    writes h_out). W_out staged to LDS (wave-private row) to cap VGPRs.

#define HID    2048
#define INS    1024
#define OUTS   1024
#define MSTEPS 100
#define NBLK   128
#define NTHR   512
#define NWAVE  8
#define JPB    16     // hidden units owned per block (128*16 = 2048)
#define RPB    64     // gate rows per block (4 gates * JPB)
#define ROWSW  8      // gate rows per wave
#define SLOTF  16     // floats per sync slot (64 B)

typedef unsigned long long u64;
typedef unsigned int u32;

__device__ __forceinline__ float wave_allreduce(float v) {
    #pragma unroll
    for (int off = 32; off > 0; off >>= 1)
        v += __shfl_xor(v, off, 64);
    return v;  // all lanes hold the sum
}

__device__ __forceinline__ u32 bf16_2(float a, float b) {   // RNE pack
    u32 ua = __float_as_uint(a), ub = __float_as_uint(b);
    ua = (ua + 0x7fffu + ((ua >> 16) & 1u)) >> 16;
    ub = (ub + 0x7fffu + ((ub >> 16) & 1u)) >> 16;
    return ua | (ub << 16);
}
__device__ __forceinline__ float blo(u32 u) { return __uint_as_float(u << 16); }
__device__ __forceinline__ float bhi(u32 u) { return __uint_as_float(u & 0xffff0000u); }

__device__ __forceinline__ u64 pack_tag(unsigned tag, float v) {
    return ((u64)tag << 32) | (u64)__float_as_uint(v);
}
__device__ __forceinline__ u64 aload(const u64* p) {
    return __hip_atomic_load(p, __ATOMIC_RELAXED, __HIP_MEMORY_SCOPE_AGENT);
}
__device__ __forceinline__ void astore(u64* p, u64 v) {
    __hip_atomic_store(p, v, __ATOMIC_RELAXED, __HIP_MEMORY_SCOPE_AGENT);
}

// ws layout (floats): [0..2048) arrive slots (128 x 64B) | [2048..4096)
// hbuf0 | [4096..6144) hbuf1.  kernel_launch zeroes 32768 bytes.

__global__
__attribute__((amdgpu_flat_work_group_size(NTHR, NTHR)))
__attribute__((amdgpu_waves_per_eu(2, 2)))
void alstm_kernel(
    const float* __restrict__ x,      const float* __restrict__ h0,
    const float* __restrict__ c0,     const float* __restrict__ W_ih,
    const float* __restrict__ b_ih,   const float* __restrict__ W_hh,
    const float* __restrict__ b_hh,   const float* __restrict__ w_halt,
    const float* __restrict__ b_halt, const float* __restrict__ W_out,
    const float* __restrict__ b_out,  float* __restrict__ out,
    float* __restrict__ ws)
{
    const int b    = blockIdx.x;
    const int tid  = threadIdx.x;
    const int wave = tid >> 6;
    const int lane = tid & 63;

    float* arrive = ws;                      // 128 x SLOTF floats
    float* hbuf0  = ws + NBLK * SLOTF;
    float* hbuf1  = hbuf0 + HID;

    __shared__ float x_lds[INS];             // 4 KB
    __shared__ float hjoint[HID];            // 8 KB: h0, later hbar stage
    __shared__ float hcur[HID];              // 8 KB: h_t for matvec
    __shared__ float wout_lds[NWAVE][HID];   // 64 KB: one W_out row per wave
    __shared__ float gate_lds[RPB];
    __shared__ float ihx_lds[RPB];
    __shared__ float psum[NWAVE];

    const int j_own = b * JPB + tid;         // valid when tid < JPB
    const int lr0   = ROWSW * wave;          // block-local rows lr0..lr0+7
    // block-local row lr -> global gate row: gate = lr>>4, unit = lr&15
    #define GR(lr_) (((lr_) >> 4) * HID + b * JPB + ((lr_) & 15))

    // ---------------- smalls (oldest in the VMEM queue) ----------------
    const float bh = b_halt[0];
    float2 xv  = ((const float2*)x)[tid];
    float4 h0v = ((const float4*)h0)[tid];
    float4 wh4 = ((const float4*)w_halt)[tid];     // halt dot, per-thread slot
    float  c_reg = (tid < JPB) ? c0[j_own] : 0.f;
    float  bo    = b_out[b * NWAVE + wave];        // uniform per wave
    float  bsum = 0.f, wflg = 0.f;
    if (lane < ROWSW) {
        const int r = GR(lr0 + lane);
        bsum = b_ih[r] + b_hh[r];
        wflg = W_ih[(size_t)r * (INS + 1)];
    }
    __builtin_amdgcn_sched_barrier(0);

    // stage x + h0 (waits only on the small loads above)
    ((float2*)x_lds)[tid]  = xv;
    ((float4*)hjoint)[tid] = h0v;
    __syncthreads();

    // ------- W_out: this wave's full row -> LDS (wave-private, no sync) ----
    {
        const float4* wr = (const float4*)(W_out + (size_t)(b * NWAVE + wave) * HID);
        float4 wv[8];
        #pragma unroll
        for (int m = 0; m < 8; ++m) wv[m] = wr[lane + 64 * m];
        #pragma unroll
        for (int m = 0; m < 8; ++m)
            ((float4*)wout_lds[wave])[lane + 64 * m] = wv[m];
    }

    // ---- ih dots: W_ih[:,1:]@x, 8 rows in 4 pipelined 2-row passes ----
    float a0=0.f,a1=0.f,a2=0.f,a3=0.f,a4=0.f,a5=0.f,a6=0.f,a7=0.f;
    #pragma unroll
    for (int ps = 0; ps < 4; ++ps) {
        const int rA = GR(lr0 + 2 * ps), rB = GR(lr0 + 2 * ps + 1);
        const float* wrA = W_ih + (size_t)rA * (INS + 1) + 1;
        const float* wrB = W_ih + (size_t)rB * (INS + 1) + 1;
        const int pA = (4 - ((rA + 1) & 3)) & 3, pB = (4 - ((rB + 1) & 3)) & 3;
        const float4* wvA = (const float4*)(wrA + pA);
        const float4* wvB = (const float4*)(wrB + pB);
        float4 bufA[4], bufB[4];
        #pragma unroll
        for (int ii = 0; ii < 4; ++ii) {
            const int i = lane + 64 * ii, ic = (i < 255) ? i : 0;
            bufA[ii] = wvA[ic];
            bufB[ii] = wvB[ic];
        }
        float sA = 0.f, sB = 0.f;
        #pragma unroll
        for (int ii = 0; ii < 4; ++ii) {
            const int i = lane + 64 * ii, ic = (i < 255) ? i : 0;
            const float msk = (i < 255) ? 1.f : 0.f;
            const int kA = pA + 4 * ic, kB = pB + 4 * ic;
            sA += msk * (bufA[ii].x * x_lds[kA]     + bufA[ii].y * x_lds[kA + 1]
                       + bufA[ii].z * x_lds[kA + 2] + bufA[ii].w * x_lds[kA + 3]);
            sB += msk * (bufB[ii].x * x_lds[kB]     + bufB[ii].y * x_lds[kB + 1]
                       + bufB[ii].z * x_lds[kB + 2] + bufB[ii].w * x_lds[kB + 3]);
        }
        if (lane < 4) {   // leftover 4 elements per row
            const int eA = (lane < pA) ? lane : 1020 + lane;
            const int eB = (lane < pB) ? lane : 1020 + lane;
            sA += wrA[eA] * x_lds[eA];
            sB += wrB[eB] * x_lds[eB];
        }
        if      (ps == 0) { a0 = sA; a1 = sB; }
        else if (ps == 1) { a2 = sA; a3 = sB; }
        else if (ps == 2) { a4 = sA; a5 = sB; }
        else              { a6 = sA; a7 = sB; }
    }

    // ---- W_hh: 8 rows -> bf16 regs (128 VGPR) + fused fp32 t=0 dot ----
    u32 wa[ROWSW][16];
    float g0=0.f,g1=0.f,g2=0.f,g3=0.f,g4=0.f,g5=0.f,g6=0.f,g7=0.f;
    #pragma unroll
    for (int ps = 0; ps < 4; ++ps) {
        const float4* sAp = (const float4*)(W_hh + (size_t)GR(lr0 + 2 * ps) * HID);
        const float4* sBp = (const float4*)(W_hh + (size_t)GR(lr0 + 2 * ps + 1) * HID);
        float4 uA[8], uB[8];
        #pragma unroll
        for (int m = 0; m < 8; ++m) { uA[m] = sAp[lane + 64 * m]; uB[m] = sBp[lane + 64 * m]; }
        float gA = 0.f, gB = 0.f;
        #pragma unroll
        for (int m = 0; m < 8; ++m) {
            float4 hh = ((const float4*)hjoint)[lane + 64 * m];
            gA += uA[m].x*hh.x + uA[m].y*hh.y + uA[m].z*hh.z + uA[m].w*hh.w;
            gB += uB[m].x*hh.x + uB[m].y*hh.y + uB[m].z*hh.z + uB[m].w*hh.w;
            wa[2*ps  ][2*m]   = bf16_2(uA[m].x, uA[m].y);
            wa[2*ps  ][2*m+1] = bf16_2(uA[m].z, uA[m].w);
            wa[2*ps+1][2*m]   = bf16_2(uB[m].x, uB[m].y);
            wa[2*ps+1][2*m+1] = bf16_2(uB[m].z, uB[m].w);
        }
        if      (ps == 0) { g0 = gA; g1 = gB; }
        else if (ps == 1) { g2 = gA; g3 = gB; }
        else if (ps == 2) { g4 = gA; g5 = gB; }
        else              { g6 = gA; g7 = gB; }
    }

    a0 = wave_allreduce(a0); a1 = wave_allreduce(a1);
    a2 = wave_allreduce(a2); a3 = wave_allreduce(a3);
    a4 = wave_allreduce(a4); a5 = wave_allreduce(a5);
    a6 = wave_allreduce(a6); a7 = wave_allreduce(a7);
    g0 = wave_allreduce(g0); g1 = wave_allreduce(g1);
    g2 = wave_allreduce(g2); g3 = wave_allreduce(g3);
    g4 = wave_allreduce(g4); g5 = wave_allreduce(g5);
    g6 = wave_allreduce(g6); g7 = wave_allreduce(g7);
    if (lane < ROWSW) {
        float av = (lane==0)?a0:(lane==1)?a1:(lane==2)?a2:(lane==3)?a3
                 : (lane==4)?a4:(lane==5)?a5:(lane==6)?a6:a7;
        float gv = (lane==0)?g0:(lane==1)?g1:(lane==2)?g2:(lane==3)?g3
                 : (lane==4)?g4:(lane==5)?g5:(lane==6)?g6:g7;
        const int idx = lr0 + lane;
        ihx_lds[idx]  = av + bsum;                // reused every step
        gate_lds[idx] = av + bsum + wflg + gv;    // t=0 gates (flag=1)
    }
    __syncthreads();                              // gate_lds ready

    // ---- t=0 unit update: H[0] for own units, publish + arrive(1) ----
    float h_reg = 0.f;
    if (tid < JPB) {
        float iv = gate_lds[0 * JPB + tid];
        float fv = gate_lds[1 * JPB + tid];
        float gv = gate_lds[2 * JPB + tid];
        float ov = gate_lds[3 * JPB + tid];
        iv = 1.f / (1.f + expf(-iv));
        fv = 1.f / (1.f + expf(-fv));
        gv = tanhf(gv);
        ov = 1.f / (1.f + expf(-ov));
        c_reg = fv * c_reg + iv * gv;
        h_reg = ov * tanhf(c_reg);
        hbuf0[j_own] = h_reg;
    }
    if (tid == 0) {                 // same wave as the stores above
        __threadfence();
        astore((u64*)(arrive + SLOTF * b), pack_tag(1u, 0.f));
    }

    // ------------- recurrence: one flat barrier per step -------------
    float4 hb4 = make_float4(0.f, 0.f, 0.f, 0.f);   // hbar (per-thread slot)
    float  cbar = 0.f, csum = 0.f, r_halt = 0.f;
    int    n_halt = 0;
    for (int t = 0; t <= MSTEPS; ++t) {
        // ---- all-to-all barrier: wait until all blocks published H[t] ----
        if (tid < NBLK) {
            u64 v = aload((u64*)(arrive + SLOTF * tid));
            while ((u32)(v >> 32) < (u32)(t + 1)) {
                __builtin_amdgcn_s_sleep(1);
                v = aload((u64*)(arrive + SLOTF * tid));
            }
        }
        __syncthreads();
        if (tid == 0) __threadfence();   // acquire: invalidate stale lines
        __syncthreads();

        // ---- read H[t]; local halt dot; hbar accumulate ----
        const float* hsrc = (t & 1) ? hbuf1 : hbuf0;
        float4 hv = ((const float4*)hsrc)[tid];
        ((float4*)hcur)[tid] = hv;
        float part = hv.x * wh4.x + hv.y * wh4.y + hv.z * wh4.z + hv.w * wh4.w;
        part = wave_allreduce(part);
        if (lane == 0) psum[wave] = part;
        __syncthreads();                 // hcur + psum ready
        float dotv = psum[0] + psum[1] + psum[2] + psum[3]
                   + psum[4] + psum[5] + psum[6] + psum[7];  // fixed order
        float p = 1.f / (1.f + expf(-(dotv + bh)));
        float prev = csum;
        csum += p;
        bool  halt_now = (csum >= 1.f - 0.01f) || (t == MSTEPS);
        float wt = halt_now ? (1.f - prev) : p;
        hb4.x += wt * hv.x; hb4.y += wt * hv.y;
        hb4.z += wt * hv.z; hb4.w += wt * hv.w;
        if (tid < JPB) cbar += wt * c_reg;
        if (halt_now) { n_halt = t; r_halt = 1.f - prev; break; }  // uniform

        // ---- gates for step t+1: bf16 regs x fp32 hcur ----
        float m0=0.f,m1=0.f,m2=0.f,m3=0.f,m4=0.f,m5=0.f,m6=0.f,m7=0.f;
        #pragma unroll
        for (int mm = 0; mm < 8; ++mm) {
            float4 hh = ((const float4*)hcur)[lane + 64 * mm];
            #pragma unroll
            for (int rr = 0; rr < ROWSW; ++rr) {
                u32 wlo = wa[rr][2 * mm], whi = wa[rr][2 * mm + 1];
                float s = blo(wlo) * hh.x + bhi(wlo) * hh.y
                        + blo(whi) * hh.z + bhi(whi) * hh.w;
                if      (rr == 0) m0 += s;
                else if (rr == 1) m1 += s;
                else if (rr == 2) m2 += s;
                else if (rr == 3) m3 += s;
                else if (rr == 4) m4 += s;
                else if (rr == 5) m5 += s;
                else if (rr == 6) m6 += s;
                else              m7 += s;
            }
        }
        m0 = wave_allreduce(m0); m1 = wave_allreduce(m1);
        m2 = wave_allreduce(m2); m3 = wave_allreduce(m3);
        m4 = wave_allreduce(m4); m5 = wave_allreduce(m5);
        m6 = wave_allreduce(m6); m7 = wave_allreduce(m7);
        if (lane < ROWSW) {
            float mv = (lane==0)?m0:(lane==1)?m1:(lane==2)?m2:(lane==3)?m3
                     : (lane==4)?m4:(lane==5)?m5:(lane==6)?m6:m7;
            gate_lds[lr0 + lane] = ihx_lds[lr0 + lane] + mv;
        }
        __syncthreads();                 // gate_lds ready

        // ---- unit update: H[t+1] own units, publish + arrive(t+2) ----
        if (tid < JPB) {
            float iv = gate_lds[0 * JPB + tid];
            float fv = gate_lds[1 * JPB + tid];
            float gv = gate_lds[2 * JPB + tid];
            float ov = gate_lds[3 * JPB + tid];
            iv = 1.f / (1.f + expf(-iv));
            fv = 1.f / (1.f + expf(-fv));
            gv = tanhf(gv);
            ov = 1.f / (1.f + expf(-ov));
            c_reg = fv * c_reg + iv * gv;
            h_reg = ov * tanhf(c_reg);
            ((t & 1) ? hbuf0 : hbuf1)[j_own] = h_reg;
        }
        if (tid == 0) {                  // same wave as the stores above
            __threadfence();
            astore((u64*)(arrive + SLOTF * b), pack_tag((u32)(t + 2), 0.f));
        }
    }

    // ------------- epilogue (no grid sync) -------------
    ((float4*)hjoint)[tid] = hb4;                  // stage hbar for W_out
    if (b == 0) ((float4*)(out + OUTS))[tid] = hb4;   // h_out (identical in
                                                      //  all blocks)
    if (tid < JPB) out[OUTS + HID + j_own] = cbar;    // c_out
    if (b == 0 && tid == 0) out[OUTS + 2 * HID] = (float)(n_halt + 1) + r_halt;
    __syncthreads();                               // hjoint ready

    // output rows: one per wave, W_out row staged in LDS
    {
        float acc = 0.f;
        #pragma unroll
        for (int m = 0; m < 8; ++m) {
            float4 w4 = ((const float4*)wout_lds[wave])[lane + 64 * m];
            float4 h4 = ((const float4*)hjoint)[lane + 64 * m];
            acc += w4.x * h4.x + w4.y * h4.y + w4.z * h4.z + w4.w * h4.w;
        }
        acc = wave_allreduce(acc);
        if (lane == 0) out[b * NWAVE + wave] = acc + bo;
    }
    #undef GR
}

extern "C" void kernel_launch(void* const* d_in, const int* in_sizes, int n_in,
                              void* d_out, int out_size, void* d_ws, size_t ws_size,
                              hipStream_t stream) {
    const float* x      = (const float*)d_in[0];
    const float* h0     = (const float*)d_in[1];
    const float* c0     = (const float*)d_in[2];
    const float* W_ih   = (const float*)d_in[3];
    const float* b_ih   = (const float*)d_in[4];
    const float* W_hh   = (const float*)d_in[5];
    const float* b_hh   = (const float*)d_in[6];
    const float* w_halt = (const float*)d_in[7];
    const float* b_halt = (const float*)d_in[8];
    const float* W_out  = (const float*)d_in[9];
    const float* b_out  = (const float*)d_in[10];
    float* out = (float*)d_out;
    float* ws  = (float*)d_ws;

    // Zero arrive slots (+slack). ws is poisoned 0xAA by the harness.
    hipMemsetAsync(d_ws, 0, 32768, stream);

    alstm_kernel<<<dim3(NBLK), dim3(NTHR), 0, stream>>>(
        x, h0, c0, W_ih, b_ih, W_hh, b_hh, w_halt, b_halt, W_out, b_out,
        out, ws);
}

// Round 5
// 155.529 us; speedup vs baseline: 1.3818x; 1.3818x over previous
//
#include <hip/hip_runtime.h>

// ALSTM: adaptive-computation-time LSTM (halts at t=1 for this data; exact
// for general n).
// R16: R14 datapath UNCHANGED (register-resident fp32 W_hh, no spills,
// proven 55us) + flat fence-free grid sync. Evidence: R14 cold (988 GB/s)
// and warm (~0 HBM) dispatches both take 55us -> the tail is not data
// movement; prime suspect is the sync path: __threadfence on gfx950 =
// full-L2 buffer_wbl2/buffer_inv, plus a block-0 hub round (poll 256 ->
// reduce -> 256 mailboxes -> poll) serialized on the straggler, twice
// per step.
//  - Hub + mailboxes DELETED. One flat round per step: owning threads
//    publish h as agent-scope RELAXED atomic stores (write through to the
//    coherence point), s_waitcnt vmcnt(0), bump arrive counter; all
//    blocks poll the 256 counters, then read full H with agent-scope
//    relaxed atomic loads (bypass stale L2). NO threadfence anywhere.
//  - Halt dot computed redundantly per block from the H it reads anyway
//    (w_halt in registers); fixed reduction order -> bit-identical p in
//    every block -> uniform halt. hbar = per-thread register float4.
//  - R15 post-mortem: 49 MB spills (wa[8][16] blew the reg file) - that
//    round was confounded; this round changes ONLY the sync topology.

#define HID    2048
#define INS    1024
#define OUTS   1024
#define MSTEPS 100
#define NBLK   256
#define NTHR   512
#define NWAVE  8
#define JPB    8      // hidden units owned per block (256*8 = 2048)
#define RPB    32     // gate rows per block (4 gates * JPB)
#define SLOTF  16     // floats per sync slot (64 B)

typedef unsigned long long u64;
typedef unsigned int u32;

__device__ __forceinline__ float wave_allreduce(float v) {
    #pragma unroll
    for (int off = 32; off > 0; off >>= 1)
        v += __shfl_xor(v, off, 64);
    return v;  // all lanes hold the sum
}

__device__ __forceinline__ u64 aload(const u64* p) {
    return __hip_atomic_load(p, __ATOMIC_RELAXED, __HIP_MEMORY_SCOPE_AGENT);
}
__device__ __forceinline__ void astore(u64* p, u64 v) {
    __hip_atomic_store(p, v, __ATOMIC_RELAXED, __HIP_MEMORY_SCOPE_AGENT);
}
__device__ __forceinline__ void astoref(float* p, float v) {
    __hip_atomic_store(p, v, __ATOMIC_RELAXED, __HIP_MEMORY_SCOPE_AGENT);
}

// ws layout (floats): [0..4096) arrive slots (256 x 64B) | [4096..6144)
// hbuf0 | [6144..8192) hbuf1.  kernel_launch zeroes 32768 bytes.

__global__
__attribute__((amdgpu_flat_work_group_size(NTHR, NTHR)))
__attribute__((amdgpu_waves_per_eu(2, 2)))
void alstm_kernel(
    const float* __restrict__ x,      const float* __restrict__ h0,
    const float* __restrict__ c0,     const float* __restrict__ W_ih,
    const float* __restrict__ b_ih,   const float* __restrict__ W_hh,
    const float* __restrict__ b_hh,   const float* __restrict__ w_halt,
    const float* __restrict__ b_halt, const float* __restrict__ W_out,
    const float* __restrict__ b_out,  float* __restrict__ out,
    float* __restrict__ ws)
{
    const int b    = blockIdx.x;
    const int tid  = threadIdx.x;
    const int wave = tid >> 6;
    const int lane = tid & 63;

    float* arrive = ws;                 // 256 x SLOTF floats (u64 counters)
    float* hbuf0  = ws + NBLK * SLOTF;
    float* hbuf1  = hbuf0 + HID;

    __shared__ float x_lds[INS];          // 4 KB
    __shared__ float hjoint[HID];         // 8 KB: h0 (t=0 dot), hbar at end
    __shared__ float hcur[HID];           // 8 KB: h_t broadcast for matvec
    __shared__ float gate_lds[RPB];
    __shared__ float ihx_lds[RPB];
    __shared__ float psum[NWAVE];

    const int j_own = b * JPB + tid;      // valid when tid < JPB
    const int lr0   = 4 * wave;           // rows lr0..lr0+3 ; lr = gate*8+unit
    const int rbase = (lr0 >> 3) * HID + b * JPB + (lr0 & 7);

    // W_hh@h dot: 4 rows (register-resident) vs a fp32 vector in LDS.
    #define DOT4(H4P, G0, G1, G2, G3) do {                                     \
        const float4* h4__ = (H4P);                                            \
        _Pragma("unroll")                                                      \
        for (int m = 0; m < 8; ++m) {                                          \
            float4 hh = h4__[lane + 64 * m];                                   \
            G0 += wa0[m].x*hh.x + wa0[m].y*hh.y + wa0[m].z*hh.z + wa0[m].w*hh.w; \
            G1 += wa1[m].x*hh.x + wa1[m].y*hh.y + wa1[m].z*hh.z + wa1[m].w*hh.w; \
            G2 += wa2[m].x*hh.x + wa2[m].y*hh.y + wa2[m].z*hh.z + wa2[m].w*hh.w; \
            G3 += wa3[m].x*hh.x + wa3[m].y*hh.y + wa3[m].z*hh.z + wa3[m].w*hh.w; \
        }                                                                      \
    } while (0)

    // ---------------- Group A: smalls (oldest in the queue) ----------------
    const float bh = b_halt[0];
    float2 xv  = ((const float2*)x)[tid];
    float4 h0v = ((const float4*)h0)[tid];
    float4 wh4 = ((const float4*)w_halt)[tid];    // halt dot, per-thread slot
    float c_reg = (tid < JPB) ? c0[j_own] : 0.f;
    float bo    = (tid < 4)   ? b_out[b * 4 + tid] : 0.f;
    float bsum = 0.f, wflg = 0.f;
    if (lane < 4) {
        const int lr = lr0 + lane;
        const int r  = (lr >> 3) * HID + b * JPB + (lr & 7);
        bsum = b_ih[r] + b_hh[r];
        wflg = W_ih[(size_t)r * (INS + 1)];
    }
    __builtin_amdgcn_sched_barrier(0);

    // ---------------- Group B: W_ih 4 rows x 4 float4 ----------------
    const float*  wr_[4];
    const float4* wv_[4];
    int p0_[4];
    #pragma unroll
    for (int rr = 0; rr < 4; ++rr) {
        const int lr = lr0 + rr;
        const int r  = (lr >> 3) * HID + b * JPB + (lr & 7);
        wr_[rr] = W_ih + (size_t)r * (INS + 1) + 1;   // payload
        p0_[rr] = (4 - ((r + 1) & 3)) & 3;
        wv_[rr] = (const float4*)(wr_[rr] + p0_[rr]);
    }
    float4 iw0[4], iw1[4], iw2[4], iw3[4];
    #pragma unroll
    for (int ii = 0; ii < 4; ++ii) {
        const int i  = lane + 64 * ii;
        const int ic = (i < 255) ? i : 0;   // clamp; masked at accumulate
        iw0[ii] = wv_[0][ic];
        iw1[ii] = wv_[1][ic];
        iw2[ii] = wv_[2][ic];
        iw3[ii] = wv_[3][ic];
    }
    __builtin_amdgcn_sched_barrier(0);

    // ------- Group C: W_hh 4 rows x 8 float4 -> registers (128 VGPR) -------
    float4 wa0[8], wa1[8], wa2[8], wa3[8];
    {
        const float4* s0 = (const float4*)(W_hh + (size_t)(rbase + 0) * HID);
        const float4* s1 = (const float4*)(W_hh + (size_t)(rbase + 1) * HID);
        const float4* s2 = (const float4*)(W_hh + (size_t)(rbase + 2) * HID);
        const float4* s3 = (const float4*)(W_hh + (size_t)(rbase + 3) * HID);
        #pragma unroll
        for (int m = 0; m < 8; ++m) {
            wa0[m] = s0[lane + 64 * m];
            wa1[m] = s1[lane + 64 * m];
            wa2[m] = s2[lane + 64 * m];
            wa3[m] = s3[lane + 64 * m];
        }
    }
    __builtin_amdgcn_sched_barrier(0);

    // ------- Group D: W_out 4 float4 (half-row per wave) -> registers -------
    const int orow  = b * 4 + (wave & 3);
    const int ohalf = wave >> 2;
    const float4* wrow = (const float4*)(W_out + (size_t)orow * HID) + ohalf * 256;
    float4 wo0 = wrow[lane], wo1 = wrow[lane + 64],
           wo2 = wrow[lane + 128], wo3 = wrow[lane + 192];
    __builtin_amdgcn_sched_barrier(0);

    // stage x + h0 (waits only on Group A; B/C/D stay in flight)
    ((float2*)x_lds)[tid]  = xv;
    ((float4*)hjoint)[tid] = h0v;        // hjoint = fp32 h0 for fused t=0 dot
    __syncthreads();

    // ---- x-dots: W_ih[:,1:]@x, 4 rows (consumes Group B) ----
    float a0 = 0.f, a1 = 0.f, a2 = 0.f, a3 = 0.f;
    #pragma unroll
    for (int ii = 0; ii < 4; ++ii) {
        const int   i   = lane + 64 * ii;
        const int   ic  = (i < 255) ? i : 0;
        const float msk = (i < 255) ? 1.f : 0.f;
        #pragma unroll
        for (int rr = 0; rr < 4; ++rr) {
            float4 w4 = (rr == 0) ? iw0[ii] : (rr == 1) ? iw1[ii]
                      : (rr == 2) ? iw2[ii] : iw3[ii];
            const int k = p0_[rr] + 4 * ic;
            float s = w4.x * x_lds[k]     + w4.y * x_lds[k + 1]
                    + w4.z * x_lds[k + 2] + w4.w * x_lds[k + 3];
            s *= msk;
            if      (rr == 0) a0 += s;
            else if (rr == 1) a1 += s;
            else if (rr == 2) a2 += s;
            else              a3 += s;
        }
    }
    if (lane < 4) {   // leftover 4 elements per row
        #pragma unroll
        for (int rr = 0; rr < 4; ++rr) {
            const int p0 = p0_[rr];
            const int e  = (lane < p0) ? lane : 1020 + lane;
            float s = wr_[rr][e] * x_lds[e];
            if      (rr == 0) a0 += s;
            else if (rr == 1) a1 += s;
            else if (rr == 2) a2 += s;
            else              a3 += s;
        }
    }

    // ---- t=0 gate dots: register W_hh vs fp32 h0 (consumes Group C) ----
    float g0 = 0.f, g1 = 0.f, g2 = 0.f, g3 = 0.f;
    DOT4((const float4*)hjoint, g0, g1, g2, g3);

    a0 = wave_allreduce(a0); a1 = wave_allreduce(a1);
    a2 = wave_allreduce(a2); a3 = wave_allreduce(a3);
    g0 = wave_allreduce(g0); g1 = wave_allreduce(g1);
    g2 = wave_allreduce(g2); g3 = wave_allreduce(g3);
    if (lane < 4) {
        float av = (lane == 0) ? a0 : (lane == 1) ? a1 : (lane == 2) ? a2 : a3;
        float gv = (lane == 0) ? g0 : (lane == 1) ? g1 : (lane == 2) ? g2 : g3;
        ihx_lds[lr0 + lane]  = av + bsum;                // reused every step
        gate_lds[lr0 + lane] = av + bsum + wflg + gv;    // t=0 gates (flag=1)
    }
    __syncthreads();                       // gate_lds ready

    // ------------- recurrence: ONE flat fence-free round per step ---------
    float4 hb4 = make_float4(0.f, 0.f, 0.f, 0.f);   // hbar (per-thread slot)
    float  h_reg = 0.f, cbar = 0.f, csum = 0.f, r_halt = 0.f;
    int    n_halt = 0;
    for (int t = 0; t <= MSTEPS; ++t) {
        // ---- unit update: own 8 units; publish via agent-scope atomics ----
        float* hdst = (t & 1) ? hbuf1 : hbuf0;
        if (tid < JPB) {
            float iv = gate_lds[0 * JPB + tid];
            float fv = gate_lds[1 * JPB + tid];
            float gv = gate_lds[2 * JPB + tid];
            float ov = gate_lds[3 * JPB + tid];
            iv = 1.f / (1.f + expf(-iv));
            fv = 1.f / (1.f + expf(-fv));
            gv = tanhf(gv);
            ov = 1.f / (1.f + expf(-ov));
            c_reg = fv * c_reg + iv * gv;
            h_reg = ov * tanhf(c_reg);
            astoref(hdst + j_own, h_reg);     // write-through to coherence pt
        }
        asm volatile("s_waitcnt vmcnt(0)" ::: "memory");  // h stores done
        if (tid == 0)
            astore((u64*)(arrive + SLOTF * b), (u64)(t + 1));

        // ---- flat barrier: poll all 256 arrive counters ----
        if (tid < NBLK) {
            const u64* slot = (const u64*)(arrive + SLOTF * tid);
            u64 v = aload(slot);
            while (v < (u64)(t + 1)) {
                __builtin_amdgcn_s_sleep(1);
                v = aload(slot);
            }
        }
        __syncthreads();

        // ---- read full H[t] via agent-scope atomic loads (bypass L2) ----
        const u64* hsrc = (const u64*)((t & 1) ? hbuf1 : hbuf0);
        u64 hA = aload(hsrc + 2 * tid);
        u64 hB = aload(hsrc + 2 * tid + 1);
        float4 hv = make_float4(__uint_as_float((u32)hA),
                                __uint_as_float((u32)(hA >> 32)),
                                __uint_as_float((u32)hB),
                                __uint_as_float((u32)(hB >> 32)));
        ((float4*)hcur)[tid] = hv;

        // ---- halt dot: redundant per block, fixed order -> uniform ----
        float part = hv.x * wh4.x + hv.y * wh4.y + hv.z * wh4.z + hv.w * wh4.w;
        part = wave_allreduce(part);
        if (lane == 0) psum[wave] = part;
        __syncthreads();                 // hcur + psum ready
        float dotv = ((psum[0] + psum[1]) + (psum[2] + psum[3]))
                   + ((psum[4] + psum[5]) + (psum[6] + psum[7]));
        float p = 1.f / (1.f + expf(-(dotv + bh)));
        float prev = csum;
        csum += p;
        bool  halt_now = (csum >= 1.f - 0.01f) || (t == MSTEPS);
        float wt = halt_now ? (1.f - prev) : p;
        hb4.x += wt * hv.x; hb4.y += wt * hv.y;
        hb4.z += wt * hv.z; hb4.w += wt * hv.w;
        if (tid < JPB) cbar += wt * c_reg;
        if (halt_now) { n_halt = t; r_halt = 1.f - prev; break; }  // uniform

        // ---- gates for step t+1: register W_hh vs fp32 hcur ----
        {
            float m0 = 0.f, m1 = 0.f, m2 = 0.f, m3 = 0.f;
            DOT4((const float4*)hcur, m0, m1, m2, m3);
            m0 = wave_allreduce(m0); m1 = wave_allreduce(m1);
            m2 = wave_allreduce(m2); m3 = wave_allreduce(m3);
            if (lane < 4) {
                float mv = (lane == 0) ? m0 : (lane == 1) ? m1
                         : (lane == 2) ? m2 : m3;
                gate_lds[lr0 + lane] = ihx_lds[lr0 + lane] + mv;
            }
        }
        __syncthreads();                 // gate_lds ready for next t
    }

    // ------------- epilogue (no grid sync) -------------
    ((float4*)hjoint)[tid] = hb4;                     // stage hbar for W_out
    if (b == 0) ((float4*)(out + OUTS))[tid] = hb4;   // h_out (identical in
                                                      //  all blocks)
    if (tid < JPB) out[OUTS + HID + j_own] = cbar;    // c_out (own units)
    if (b == 0 && tid == 0) out[OUTS + 2 * HID] = (float)(n_halt + 1) + r_halt;
    __syncthreads();                                  // hjoint ready

    // output = W_out @ hbar + b_out : W_out half-rows already in registers
    {
        const float4* hb4p = (const float4*)hjoint + ohalf * 256;
        float acc = 0.f;
        { float4 h4 = hb4p[lane];       acc += wo0.x*h4.x + wo0.y*h4.y + wo0.z*h4.z + wo0.w*h4.w; }
        { float4 h4 = hb4p[lane + 64];  acc += wo1.x*h4.x + wo1.y*h4.y + wo1.z*h4.z + wo1.w*h4.w; }
        { float4 h4 = hb4p[lane + 128]; acc += wo2.x*h4.x + wo2.y*h4.y + wo2.z*h4.z + wo2.w*h4.w; }
        { float4 h4 = hb4p[lane + 192]; acc += wo3.x*h4.x + wo3.y*h4.y + wo3.z*h4.z + wo3.w*h4.w; }
        acc = wave_allreduce(acc);
        if (lane == 0) psum[wave] = acc;
    }
    __syncthreads();
    if (tid < 4) out[b * 4 + tid] = psum[tid] + psum[tid + 4] + bo;

    #undef DOT4
}

extern "C" void kernel_launch(void* const* d_in, const int* in_sizes, int n_in,
                              void* d_out, int out_size, void* d_ws, size_t ws_size,
                              hipStream_t stream) {
    const float* x      = (const float*)d_in[0];
    const float* h0     = (const float*)d_in[1];
    const float* c0     = (const float*)d_in[2];
    const float* W_ih   = (const float*)d_in[3];
    const float* b_ih   = (const float*)d_in[4];
    const float* W_hh   = (const float*)d_in[5];
    const float* b_hh   = (const float*)d_in[6];
    const float* w_halt = (const float*)d_in[7];
    const float* b_halt = (const float*)d_in[8];
    const float* W_out  = (const float*)d_in[9];
    const float* b_out  = (const float*)d_in[10];
    float* out = (float*)d_out;
    float* ws  = (float*)d_ws;

    // Zero arrive slots (+slack). ws is poisoned 0xAA by the harness.
    hipMemsetAsync(d_ws, 0, 32768, stream);

    alstm_kernel<<<dim3(NBLK), dim3(NTHR), 0, stream>>>(
        x, h0, c0, W_ih, b_ih, W_hh, b_hh, w_halt, b_halt, W_out, b_out,
        out, ws);
}